// Round 1
// 5981.620 us; speedup vs baseline: 1.1825x; 1.1825x over previous
//
#include <hip/hip_runtime.h>

typedef unsigned short u16;
typedef unsigned int   u32;

typedef __bf16 bf16x8 __attribute__((ext_vector_type(8)));
typedef float  f32x4  __attribute__((ext_vector_type(4)));
typedef u32    u32x4  __attribute__((ext_vector_type(4)));

#define B_    32
#define S_    512
#define I_    512
#define H_    1024
#define NBLK  128                 // blocks; each owns H_/NBLK = 8 hidden units
#define HU    8
#define SLOT_ELEMS (B_ * H_)      // one h snapshot: 32768 u16 = 64 KB

__device__ __forceinline__ u16 bf16bits(float f) {
    __bf16 b = (__bf16)f;                       // HW RNE convert on gfx950
    return __builtin_bit_cast(u16, b);
}
__device__ __forceinline__ float sigmoid_(float x) {
    return 1.0f / (1.0f + __expf(-x));
}
__device__ __forceinline__ float tanh_(float x) {
    return 2.0f / (1.0f + __expf(-2.0f * x)) - 1.0f;
}

// Persistent LSTM (fp32 I/O, bf16 MFMA compute), fence-free step protocol.
// Protocol redesign vs previous version (13.8 us/step, all util counters ~1%):
//  - h ring slots are BLOCK-MAJOR: slot[kblk][batch][8 units]. Each producer
//    writes one contiguous 512 B region per step with 32 dwordx4 sc0 sc1
//    stores (full-line write-through; 4x fewer IC txns; faster vmcnt drain
//    before the publish). Reader fragment = same single 16 B load per kb.
//  - poll: ONE half-wave per block; lanes 0..31 each gather 4 packed slots
//    with global_load_dwordx4 sc0 sc1 (8 coalesced line-reqs/round/block,
//    ~16x less IC poll traffic than 2 full waves of scalar agent loads).
//    Remaining waves wait at a RAW s_barrier (no vmcnt(0) drain there).
//  - out[] stores ride in the poll shadow (h carried one step in a register,
//    stored right after the publish) instead of being drained by the barrier.
//  - h@U uses two independent 16-deep MFMA chains (halved dep latency).
__global__ void __launch_bounds__(256, 1)
lstm_kernel(const float* __restrict__ X,
            const float* __restrict__ w_i, const float* __restrict__ u_i, const float* __restrict__ b_i,
            const float* __restrict__ w_f, const float* __restrict__ u_f, const float* __restrict__ b_f,
            const float* __restrict__ w_c, const float* __restrict__ u_c, const float* __restrict__ b_c,
            const float* __restrict__ w_o, const float* __restrict__ u_o, const float* __restrict__ b_o,
            float* __restrict__ out, u16* __restrict__ hbuf,
            u32* __restrict__ slots, int ring)
{
    __shared__ float gbuf[32 * 33];   // raw gates, +1 col pad

    const int tid  = threadIdx.x;
    const int bid  = blockIdx.x;
    const int wave = tid >> 6;
    const int lane = tid & 63;
    const int rt   = wave >> 1;       // row tile (batch 16*rt..)
    const int ct   = wave & 1;        // col tile (gate cols 16*ct..)
    const int quad = lane >> 4;
    const int l16  = lane & 15;
    const int hu0  = bid * HU;

    // ---- B-operand fragments into registers (once), fp32 -> bf16 ----
    // block-local gate col: 0..31 = gate g (i,f,c,o) * 8 + unit u
    const int col = ct * 16 + l16;
    const int g   = col >> 3;
    const int u   = col & 7;
    const float* Ucol = ((g == 0) ? u_i : (g == 1) ? u_f : (g == 2) ? u_c : u_o) + hu0 + u;
    const float* Wcol = ((g == 0) ? w_i : (g == 1) ? w_f : (g == 2) ? w_c : w_o) + hu0 + u;

    bf16x8 bfr[48];                   // B[k = kb*32 + quad*8 + j][col]
    #pragma unroll
    for (int kb = 0; kb < 32; ++kb) { // K 0..1023: U rows
        #pragma unroll
        for (int j = 0; j < 8; ++j) {
            int k = kb * 32 + quad * 8 + j;
            bfr[kb][j] = (__bf16)Ucol[k * H_];
        }
    }
    #pragma unroll
    for (int kb = 32; kb < 48; ++kb) { // K 1024..1535: W rows
        #pragma unroll
        for (int j = 0; j < 8; ++j) {
            int k = kb * 32 + quad * 8 + j - 1024;
            bfr[kb][j] = (__bf16)Wcol[k * H_];
        }
    }

    // ---- update-phase ownership: thread -> (batch ub, unit uu) ----
    const int ub   = tid >> 3;        // batch 0..31
    const int uu   = tid & 7;         // unit  0..7
    const int unit = hu0 + uu;

    // h0 = 0 into ring slot 0 (block-major; drained by first barrier)
    if ((uu & 1) == 0) {
        u32* p0 = (u32*)hbuf + ((bid * 256 + ub * 8 + uu) >> 1);
        __hip_atomic_store(p0, 0u, __ATOMIC_RELAXED, __HIP_MEMORY_SCOPE_AGENT);
    }

    const float bia = b_i[unit];
    const float bif = b_f[unit];
    const float bic = b_c[unit];
    const float bio = b_o[unit];
    float cstate = 0.0f;
    float h_prev = 0.0f;

    const int    arow = rt * 16 + l16;                    // batch row this lane feeds to A
    const float* xrow = X + arow * (S_ * I_) + quad * 8;  // A[m][k]: m=lane&15(+16rt), k=quad*8+j

    for (int t = 0; t < S_; ++t) {
        // arrival: __syncthreads drains ALL waves' h stores (compiler emits
        // vmcnt(0) before s_barrier), then thread 0 publishes the round.
        __syncthreads();
        if (tid == 0)
            __hip_atomic_store(&slots[bid], (u32)(t + 1),
                               __ATOMIC_RELAXED, __HIP_MEMORY_SCOPE_AGENT);

        // out store of h(t-1): in the publish/poll shadow, off the drain path
        if (t)
            out[ub * (S_ * H_) + (t - 1) * H_ + unit] = h_prev;

        // ---- x_t @ W: h-independent, overlaps other blocks' arrival ----
        f32x4 accW = {0.f, 0.f, 0.f, 0.f};
        const float* xk = xrow + t * I_;
        #pragma unroll
        for (int kb = 0; kb < 16; ++kb) {
            f32x4 lo = *(const f32x4*)(xk + kb * 32);
            f32x4 hi = *(const f32x4*)(xk + kb * 32 + 4);
            bf16x8 a;
            a[0] = (__bf16)lo[0]; a[1] = (__bf16)lo[1];
            a[2] = (__bf16)lo[2]; a[3] = (__bf16)lo[3];
            a[4] = (__bf16)hi[0]; a[5] = (__bf16)hi[1];
            a[6] = (__bf16)hi[2]; a[7] = (__bf16)hi[3];
            accW = __builtin_amdgcn_mfma_f32_16x16x32_bf16(a, bfr[32 + kb], accW, 0, 0, 0);
        }

        // wait: lanes 0..31 each gather 4 packed slots (dwordx4, IC-scope).
        // Signed compare: 0xAAAAAAAA poison < 1.
        if (tid < 32) {
            const u32* sp = slots + (tid << 2);
            const int target = t + 1;
            for (;;) {
                u32x4 v;
                asm volatile("global_load_dwordx4 %0, %1, off sc0 sc1\n\t"
                             "s_waitcnt vmcnt(0)"
                             : "=v"(v) : "v"(sp) : "memory");
                if ((int)v[0] >= target && (int)v[1] >= target &&
                    (int)v[2] >= target && (int)v[3] >= target) break;
            }
        }
        // raw barrier: no vmcnt drain needed; "memory" stops load hoisting
        asm volatile("s_barrier" ::: "memory");

        // ---- h(t-1) @ U (block-major slot; two independent MFMA chains) ----
        const int rdslot = ring ? t : (t & 1);
        f32x4 acc  = accW;
        f32x4 acc1 = {0.f, 0.f, 0.f, 0.f};
        if (ring) {
            const u16* hb = hbuf + (size_t)rdslot * SLOT_ELEMS + arow * 8 + quad * 256;
            #pragma unroll
            for (int kb = 0; kb < 16; ++kb) {
                bf16x8 a0 = *(const bf16x8*)(hb + kb * 1024);
                acc  = __builtin_amdgcn_mfma_f32_16x16x32_bf16(a0, bfr[kb], acc, 0, 0, 0);
                bf16x8 a1 = *(const bf16x8*)(hb + (kb + 16) * 1024);
                acc1 = __builtin_amdgcn_mfma_f32_16x16x32_bf16(a1, bfr[kb + 16], acc1, 0, 0, 0);
            }
            acc += acc1;
        } else {
            const u32* hb32 = (const u32*)(hbuf + (size_t)rdslot * SLOT_ELEMS)
                              + (arow * 4 + quad * 128);
            #pragma unroll
            for (int kb = 0; kb < 32; ++kb) {
                union { u32 d[4]; bf16x8 v; } cv;
                #pragma unroll
                for (int w = 0; w < 4; ++w)
                    cv.d[w] = __hip_atomic_load(hb32 + kb * 512 + w,
                                                __ATOMIC_RELAXED, __HIP_MEMORY_SCOPE_AGENT);
                acc = __builtin_amdgcn_mfma_f32_16x16x32_bf16(cv.v, bfr[kb], acc, 0, 0, 0);
            }
        }

        // C/D layout: D[row = quad*4 + r][col = lane&15] (+16 per tile)
        {
            const int r0 = rt * 16 + quad * 4;
            #pragma unroll
            for (int r = 0; r < 4; ++r)
                gbuf[(r0 + r) * 33 + col] = acc[r];
        }
        __syncthreads();

        // gates -> c,h update (c stays in an fp32 register all 512 steps)
        {
            float gi = gbuf[ub * 33 + uu]      + bia;
            float gf = gbuf[ub * 33 + 8 + uu]  + bif;
            float gc = gbuf[ub * 33 + 16 + uu] + bic;
            float go = gbuf[ub * 33 + 24 + uu] + bio;
            float it  = sigmoid_(gi);
            float ft  = sigmoid_(gf);
            float ctl = tanh_(gc);
            float ot  = sigmoid_(go);
            cstate = ft * cstate + it * ctl;
            float h = ot * tanh_(cstate);
            h_prev = h;

            // pack 8 units (one batch row) -> one dwordx4 sc0 sc1 store from
            // the uu==0 thread of each 8-lane group (block-major region is
            // contiguous: full-line write-through, 32 stores per block)
            float hnb = __shfl_xor(h, 1);
            u32 pk = (u32)bf16bits(h) | ((u32)bf16bits(hnb) << 16);
            u32 p1 = __shfl_down(pk, 2);
            u32 p2 = __shfl_down(pk, 4);
            u32 p3 = __shfl_down(pk, 6);
            if (uu == 0) {
                const int wrslot = ring ? (t + 1) : ((t + 1) & 1);
                u32* wp = (u32*)hbuf + (size_t)wrslot * (SLOT_ELEMS / 2)
                          + bid * 128 + ub * 4;
                u32x4 q; q[0] = pk; q[1] = p1; q[2] = p2; q[3] = p3;
                asm volatile("global_store_dwordx4 %0, %1, off sc0 sc1"
                             :: "v"(wp), "v"(q) : "memory");
            }
        }
        // next iteration's barrier separates this h(t) write from readers
    }

    // tail: last hidden row + finals (kernel-end flush publishes to host)
    out[ub * (S_ * H_) + (S_ - 1) * H_ + unit] = h_prev;
    out[B_ * S_ * H_ + ub * H_ + unit] = h_prev;                  // h_t
    out[B_ * S_ * H_ + B_ * H_ + ub * H_ + unit] = cstate;        // c_t
}

extern "C" void kernel_launch(void* const* d_in, const int* in_sizes, int n_in,
                              void* d_out, int out_size, void* d_ws, size_t ws_size,
                              hipStream_t stream) {
    const float* X   = (const float*)d_in[0];
    const float* w_i = (const float*)d_in[1];
    const float* u_i = (const float*)d_in[2];
    const float* b_i = (const float*)d_in[3];
    const float* w_f = (const float*)d_in[4];
    const float* u_f = (const float*)d_in[5];
    const float* b_f = (const float*)d_in[6];
    const float* w_c = (const float*)d_in[7];
    const float* u_c = (const float*)d_in[8];
    const float* b_c = (const float*)d_in[9];
    const float* w_o = (const float*)d_in[10];
    const float* u_o = (const float*)d_in[11];
    const float* b_o = (const float*)d_in[12];
    float* out = (float*)d_out;

    // ws layout: ring of (S_+1) h slots (64 KB each) if it fits, else 2 slots
    // (alternating, sc1-load fallback); then 128 packed barrier slot dwords.
    const size_t ring_bytes = (size_t)(S_ + 1) * SLOT_ELEMS * sizeof(u16); // 33.6 MB
    const size_t fb_bytes   = (size_t)2 * SLOT_ELEMS * sizeof(u16);        // 128 KB
    int ring = (ws_size >= ring_bytes + 1024) ? 1 : 0;
    size_t slots_off = ring ? ring_bytes : fb_bytes;

    u16* hbuf  = (u16*)d_ws;
    u32* slots = (u32*)((char*)d_ws + slots_off);

    hipLaunchKernelGGL(lstm_kernel, dim3(NBLK), dim3(256), 0, stream,
                       X, w_i, u_i, b_i, w_f, u_f, b_f, w_c, u_c, b_c,
                       w_o, u_o, b_o, out, hbuf, slots, ring);
}